// Round 1
// baseline (899.366 us; speedup 1.0000x reference)
//
#include <hip/hip_runtime.h>

static constexpr int T_LEN = 1024;

__device__ __forceinline__ float fsig(float v) {
    v = fminf(fmaxf(v, -30.f), 30.f);
    return __builtin_amdgcn_rcpf(1.f + __expf(-v));
}
__device__ __forceinline__ float ftanh(float v) {
    v = fminf(fmaxf(v, -15.f), 15.f);
    const float e = __expf(-2.f * v);
    return (1.f - e) * __builtin_amdgcn_rcpf(1.f + e);
}

// One batch element per 16-lane group; lane j owns hidden unit j (gate rows
// j, 16+j, 32+j, 48+j of each 64x16 weight matrix, PyTorch i,f,g,o order).
// Layer 2 runs one step delayed so the h1 broadcast at iteration t feeds BOTH
// Whh0 (layer-1 step t) and Wih1 (layer-2 step t-1): 8 FMAs per shuffle.
__global__ __launch_bounds__(256, 1) void lstm2_fused_kernel(
    const float* __restrict__ x,
    const float* __restrict__ Wih0, const float* __restrict__ Whh0,
    const float* __restrict__ bih0, const float* __restrict__ bhh0,
    const float* __restrict__ Wih1, const float* __restrict__ Whh1,
    const float* __restrict__ bih1, const float* __restrict__ bhh1,
    const float* __restrict__ Wout, const float* __restrict__ bout,
    float* __restrict__ out)
{
    const int tid = threadIdx.x;
    const int j   = tid & 15;
    const int b   = blockIdx.x * 16 + (tid >> 4);

    // Per-lane weights in registers (all indexing compile-time after unroll).
    float w0[4][16], wx1[4][16], w1[4][16];
    float wi0[4], b0[4], b1[4];
#pragma unroll
    for (int g = 0; g < 4; ++g) {
        const int r = g * 16 + j;
        wi0[g] = Wih0[r];
        b0[g]  = bih0[r] + bhh0[r];
        b1[g]  = bih1[r] + bhh1[r];
#pragma unroll
        for (int kq = 0; kq < 4; ++kq) {
            const float4 a = *reinterpret_cast<const float4*>(Whh0 + r * 16 + kq * 4);
            w0[g][kq*4+0] = a.x;  w0[g][kq*4+1] = a.y;
            w0[g][kq*4+2] = a.z;  w0[g][kq*4+3] = a.w;
            const float4 c = *reinterpret_cast<const float4*>(Wih1 + r * 16 + kq * 4);
            wx1[g][kq*4+0] = c.x; wx1[g][kq*4+1] = c.y;
            wx1[g][kq*4+2] = c.z; wx1[g][kq*4+3] = c.w;
            const float4 d = *reinterpret_cast<const float4*>(Whh1 + r * 16 + kq * 4);
            w1[g][kq*4+0] = d.x;  w1[g][kq*4+1] = d.y;
            w1[g][kq*4+2] = d.z;  w1[g][kq*4+3] = d.w;
        }
    }

    float h1 = 0.f, c1 = 0.f, h2 = 0.f, c2 = 0.f;
    const float* xb = x + (size_t)b * T_LEN;

    // Prefetch one float4 block of x ahead (all 16 lanes of a group load the
    // same address — single fetch, L1-served).
    float4 xq = *reinterpret_cast<const float4*>(xb);

    for (int tb = 0; tb < T_LEN; tb += 4) {
        float4 xn = xq;
        if (tb + 4 < T_LEN)
            xn = *reinterpret_cast<const float4*>(xb + tb + 4);
#pragma unroll
        for (int u = 0; u < 4; ++u) {
            const float xt = (u == 0) ? xq.x : (u == 1) ? xq.y : (u == 2) ? xq.z : xq.w;
            // ---- phase 1: broadcast h1[t-1]; accumulate layer-1 gates (A*)
            //      and layer-2 input projection for step t-1 (X*).
            float A0 = fmaf(wi0[0], xt, b0[0]);
            float A1 = fmaf(wi0[1], xt, b0[1]);
            float A2 = fmaf(wi0[2], xt, b0[2]);
            float A3 = fmaf(wi0[3], xt, b0[3]);
            float X0 = b1[0], X1 = b1[1], X2 = b1[2], X3 = b1[3];
#pragma unroll
            for (int k = 0; k < 16; ++k) {
                const float hk = __shfl(h1, k, 16);
                A0 = fmaf(w0[0][k], hk, A0);
                A1 = fmaf(w0[1][k], hk, A1);
                A2 = fmaf(w0[2][k], hk, A2);
                A3 = fmaf(w0[3][k], hk, A3);
                X0 = fmaf(wx1[0][k], hk, X0);
                X1 = fmaf(wx1[1][k], hk, X1);
                X2 = fmaf(wx1[2][k], hk, X2);
                X3 = fmaf(wx1[3][k], hk, X3);
            }
            // ---- phase 2: layer-2 step t-1 (skipped at t==0; branch is
            //      uniform across the whole grid).
            if (tb + u > 0) {
                float B0 = X0, B1 = X1, B2 = X2, B3 = X3;
#pragma unroll
                for (int k = 0; k < 16; ++k) {
                    const float hk = __shfl(h2, k, 16);
                    B0 = fmaf(w1[0][k], hk, B0);
                    B1 = fmaf(w1[1][k], hk, B1);
                    B2 = fmaf(w1[2][k], hk, B2);
                    B3 = fmaf(w1[3][k], hk, B3);
                }
                const float i2 = fsig(B0), f2 = fsig(B1);
                const float g2 = ftanh(B2), o2 = fsig(B3);
                c2 = fmaf(f2, c2, i2 * g2);
                h2 = o2 * ftanh(c2);
            }
            // ---- phase 3: layer-1 activations/update.
            const float i1 = fsig(A0), f1 = fsig(A1);
            const float g1 = ftanh(A2), o1 = fsig(A3);
            c1 = fmaf(f1, c1, i1 * g1);
            h1 = o1 * ftanh(c1);
        }
        xq = xn;
    }

    // ---- final layer-2 step (t = T-1): Wih1@h1[T-1] + Whh1@h2[T-2].
    {
        float B0 = b1[0], B1 = b1[1], B2 = b1[2], B3 = b1[3];
#pragma unroll
        for (int k = 0; k < 16; ++k) {
            const float hk = __shfl(h1, k, 16);
            B0 = fmaf(wx1[0][k], hk, B0);
            B1 = fmaf(wx1[1][k], hk, B1);
            B2 = fmaf(wx1[2][k], hk, B2);
            B3 = fmaf(wx1[3][k], hk, B3);
        }
#pragma unroll
        for (int k = 0; k < 16; ++k) {
            const float hk = __shfl(h2, k, 16);
            B0 = fmaf(w1[0][k], hk, B0);
            B1 = fmaf(w1[1][k], hk, B1);
            B2 = fmaf(w1[2][k], hk, B2);
            B3 = fmaf(w1[3][k], hk, B3);
        }
        const float i2 = fsig(B0), f2 = fsig(B1);
        const float g2 = ftanh(B2), o2 = fsig(B3);
        c2 = fmaf(f2, c2, i2 * g2);
        h2 = o2 * ftanh(c2);
    }

    // ---- head: out[b][m] = relu(h2) . Wout[m] + bout[m]
    const float rh = fmaxf(h2, 0.f);
#pragma unroll
    for (int m = 0; m < 5; ++m) {
        float p = rh * Wout[m * 16 + j];
        p += __shfl_xor(p, 1, 16);
        p += __shfl_xor(p, 2, 16);
        p += __shfl_xor(p, 4, 16);
        p += __shfl_xor(p, 8, 16);
        if (j == m) out[b * 5 + m] = p + bout[m];
    }
}

extern "C" void kernel_launch(void* const* d_in, const int* in_sizes, int n_in,
                              void* d_out, int out_size, void* d_ws, size_t ws_size,
                              hipStream_t stream) {
    const float* x    = (const float*)d_in[0];
    const float* Wih0 = (const float*)d_in[1];
    const float* Whh0 = (const float*)d_in[2];
    const float* bih0 = (const float*)d_in[3];
    const float* bhh0 = (const float*)d_in[4];
    const float* Wih1 = (const float*)d_in[5];
    const float* Whh1 = (const float*)d_in[6];
    const float* bih1 = (const float*)d_in[7];
    const float* bhh1 = (const float*)d_in[8];
    const float* Wout = (const float*)d_in[9];
    const float* bout = (const float*)d_in[10];
    float* out = (float*)d_out;

    const int B = in_sizes[0] / T_LEN;          // 4096
    dim3 grid(B / 16), block(256);              // 16 sequences per block
    hipLaunchKernelGGL(lstm2_fused_kernel, grid, block, 0, stream,
                       x, Wih0, Whh0, bih0, bhh0,
                       Wih1, Whh1, bih1, bhh1, Wout, bout, out);
}

// Round 2
// 870.117 us; speedup vs baseline: 1.0336x; 1.0336x over previous
//
#include <hip/hip_runtime.h>

static constexpr int T_LEN = 1024;

__device__ __forceinline__ float bcastf(float v, int l) {
    // wave-uniform broadcast from literal lane -> SGPR (v_readlane_b32)
    return __uint_as_float(__builtin_amdgcn_readlane(__float_as_uint(v), l));
}
// 1/(1+2^t): overflow-safe (t->+inf: exp2=inf, rcp(inf)=0; t->-inf: ->1)
__device__ __forceinline__ float sig2(float t) {
    return __builtin_amdgcn_rcpf(1.f + __builtin_amdgcn_exp2f(t));
}

// One wave (64 lanes) per batch element. Lane r = g*16+j owns gate row r
// (PyTorch i,f,g,o order) of Whh0, Wih1, Whh1. Hidden state h/c for unit
// j=lane&15 is replicated across the 4 gate groups, so v_readlane k (k<16)
// broadcasts h[k]. Layer 2 runs TWO steps delayed via a saved projection Xp,
// so the layer-1 and layer-2 FMA chains are independent within an iteration.
__global__ __launch_bounds__(256, 4) void lstm2_w64_kernel(
    const float* __restrict__ x,
    const float* __restrict__ Wih0, const float* __restrict__ Whh0,
    const float* __restrict__ bih0, const float* __restrict__ bhh0,
    const float* __restrict__ Wih1, const float* __restrict__ Whh1,
    const float* __restrict__ bih1, const float* __restrict__ bhh1,
    const float* __restrict__ Wout, const float* __restrict__ bout,
    float* __restrict__ out)
{
    const int tid  = threadIdx.x;
    const int lane = tid & 63;
    const int j    = lane & 15;
    const int gi   = lane >> 4;
    const int b    = blockIdx.x * 4 + (tid >> 6);

    // Per-lane weight rows in registers (static indexing after unroll).
    float w0r[16], wx1r[16], w1r[16];
#pragma unroll
    for (int q = 0; q < 4; ++q) {
        const float4 a = *reinterpret_cast<const float4*>(Whh0 + lane * 16 + q * 4);
        w0r[q*4+0]=a.x; w0r[q*4+1]=a.y; w0r[q*4+2]=a.z; w0r[q*4+3]=a.w;
        const float4 c = *reinterpret_cast<const float4*>(Wih1 + lane * 16 + q * 4);
        wx1r[q*4+0]=c.x; wx1r[q*4+1]=c.y; wx1r[q*4+2]=c.z; wx1r[q*4+3]=c.w;
        const float4 d = *reinterpret_cast<const float4*>(Whh1 + lane * 16 + q * 4);
        w1r[q*4+0]=d.x; w1r[q*4+1]=d.y; w1r[q*4+2]=d.z; w1r[q*4+3]=d.w;
    }
    const float wi0 = Wih0[lane];
    const float bb0 = bih0[lane] + bhh0[lane];
    const float bb1 = bih1[lane] + bhh1[lane];

    // Activation constants: gate rows g==2 use tanh = 2*sig(2v)-1.
    const bool  isg  = (gi == 2);
    const float nsc  = isg ? -2.885390082f : -1.442695041f;  // -scale*log2(e)
    const float amul = isg ? 2.f : 1.f;
    const float aadd = isg ? -1.f : 0.f;
    const float NT   = -2.885390082f;                        // for tanh(c)

    float h1 = 0.f, c1 = 0.f, h2 = 0.f, c2 = 0.f, Xp = 0.f;

    const float* xb = x + (size_t)b * T_LEN;
    float4 xq = *reinterpret_cast<const float4*>(xb);

    for (int tb = 0; tb < T_LEN; tb += 4) {
        float4 xn = xq;
        if (tb + 4 < T_LEN)
            xn = *reinterpret_cast<const float4*>(xb + tb + 4);
#pragma unroll
        for (int u = 0; u < 4; ++u) {
            const int   t  = tb + u;
            const float xt = (u==0)?xq.x:(u==1)?xq.y:(u==2)?xq.z:xq.w;

            // Layer-1 gates for step t + projection of h1[t-1] (shared
            // readlane feeds both row sets).
            float A = fmaf(wi0, xt, bb0);
            float X = bb1;
#pragma unroll
            for (int k = 0; k < 16; ++k) {
                const float hk = bcastf(h1, k);
                A = fmaf(w0r[k],  hk, A);
                X = fmaf(wx1r[k], hk, X);
            }

            // Layer-2 step t-2: uses Xp = proj(h1[t-2]) and h2[t-3].
            // Independent of the loop above -> scheduler interleaves.
            if (t >= 2) {
                float B = Xp;
#pragma unroll
                for (int k = 0; k < 16; ++k)
                    B = fmaf(w1r[k], bcastf(h2, k), B);
                const float act2 = fmaf(amul, sig2(nsc * B), aadd);
                const float i2 = __shfl(act2, j,      64);
                const float f2 = __shfl(act2, j + 16, 64);
                const float g2 = __shfl(act2, j + 32, 64);
                const float o2 = __shfl(act2, j + 48, 64);
                c2 = fmaf(f2, c2, i2 * g2);
                h2 = o2 * fmaf(2.f, sig2(NT * c2), -1.f);
            }

            // Layer-1 activation + state update.
            {
                const float act1 = fmaf(amul, sig2(nsc * A), aadd);
                const float i1 = __shfl(act1, j,      64);
                const float f1 = __shfl(act1, j + 16, 64);
                const float g1 = __shfl(act1, j + 32, 64);
                const float o1 = __shfl(act1, j + 48, 64);
                c1 = fmaf(f1, c1, i1 * g1);
                h1 = o1 * fmaf(2.f, sig2(NT * c1), -1.f);
            }
            Xp = X;
        }
        xq = xn;
    }

    // Epilogue: layer-2 steps T-2 (from Xp, h2[T-3]) and T-1 (from h1[T-1]).
#pragma unroll
    for (int e = 0; e < 2; ++e) {
        float B;
        if (e == 0) {
            B = Xp;
        } else {
            B = bb1;
#pragma unroll
            for (int k = 0; k < 16; ++k)
                B = fmaf(wx1r[k], bcastf(h1, k), B);
        }
#pragma unroll
        for (int k = 0; k < 16; ++k)
            B = fmaf(w1r[k], bcastf(h2, k), B);
        const float act2 = fmaf(amul, sig2(nsc * B), aadd);
        const float i2 = __shfl(act2, j,      64);
        const float f2 = __shfl(act2, j + 16, 64);
        const float g2 = __shfl(act2, j + 32, 64);
        const float o2 = __shfl(act2, j + 48, 64);
        c2 = fmaf(f2, c2, i2 * g2);
        h2 = o2 * fmaf(2.f, sig2(NT * c2), -1.f);
    }

    // Head: out[b][m] = relu(h2) . Wout[m] + bout[m]
    const float rh = fmaxf(h2, 0.f);
#pragma unroll
    for (int m = 0; m < 5; ++m) {
        float p = rh * Wout[m * 16 + j];
        p += __shfl_xor(p, 1, 16);
        p += __shfl_xor(p, 2, 16);
        p += __shfl_xor(p, 4, 16);
        p += __shfl_xor(p, 8, 16);
        if (lane == m) out[b * 5 + m] = p + bout[m];
    }
}

extern "C" void kernel_launch(void* const* d_in, const int* in_sizes, int n_in,
                              void* d_out, int out_size, void* d_ws, size_t ws_size,
                              hipStream_t stream) {
    const float* x    = (const float*)d_in[0];
    const float* Wih0 = (const float*)d_in[1];
    const float* Whh0 = (const float*)d_in[2];
    const float* bih0 = (const float*)d_in[3];
    const float* bhh0 = (const float*)d_in[4];
    const float* Wih1 = (const float*)d_in[5];
    const float* Whh1 = (const float*)d_in[6];
    const float* bih1 = (const float*)d_in[7];
    const float* bhh1 = (const float*)d_in[8];
    const float* Wout = (const float*)d_in[9];
    const float* bout = (const float*)d_in[10];
    float* out = (float*)d_out;

    const int B = in_sizes[0] / T_LEN;          // 4096
    dim3 grid(B / 4), block(256);               // 1 wave per sequence
    hipLaunchKernelGGL(lstm2_w64_kernel, grid, block, 0, stream,
                       x, Wih0, Whh0, bih0, bhh0,
                       Wih1, Whh1, bih1, bhh1, Wout, bout, out);
}